// Round 2
// baseline (174.017 us; speedup 1.0000x reference)
//
#include <hip/hip_runtime.h>

#define W_OUT 3840
#define H_OUT 2160
#define IW 1024   // intermediate (cropped) cols
#define IH 576    // intermediate (cropped) rows

__device__ __forceinline__ unsigned int enc_f32(float f) {
    // order-preserving float->uint map (monotone for ALL floats)
    unsigned int b = __float_as_uint(f);
    return b ^ (0x80000000u | (unsigned int)((int)b >> 31));
}

// Kernel 1: sim64[p] = sum_c ref[c]*emb[c][p] / sqrt(sum_c emb[c][p]^2)
// KEEP ARITHMETIC EXACTLY AS ROUND 1 (bitwise-matched the reference).
__global__ __launch_bounds__(256) void sim_kernel(
    const float* __restrict__ emb, const float* __restrict__ ref,
    float* __restrict__ sim, unsigned long long* __restrict__ cells,
    unsigned long long* __restrict__ bg)
{
    const int lane = threadIdx.x & 63;
    const int wave = threadIdx.x >> 6;
    const int p = blockIdx.x * 64 + lane;
    const int cbase = wave * 64;
    float dot = 0.f, ss = 0.f;
#pragma unroll 8
    for (int cc = 0; cc < 64; ++cc) {
        int c = cbase + cc;
        float a = emb[c * 4096 + p];
        dot = fmaf(ref[c], a, dot);
        ss  = fmaf(a, a, ss);
    }
    __shared__ float sdot[4][64];
    __shared__ float sss[4][64];
    sdot[wave][lane] = dot;
    sss[wave][lane]  = ss;
    __syncthreads();
    if (wave == 0) {
        float d = (sdot[0][lane] + sdot[1][lane]) + (sdot[2][lane] + sdot[3][lane]);
        float s = (sss[0][lane] + sss[1][lane]) + (sss[2][lane] + sss[3][lane]);
        sim[p] = d / sqrtf(s);
    }
    // init reduction slots (ws is poisoned 0xAA before every launch)
    if (blockIdx.x == 0) {
        cells[threadIdx.x] = 0ull;
        if (threadIdx.x == 0) *bg = 0xFFFFFFFFFFFFFFFFull;
    }
}

// Kernel 2: one block per output row y (2160 blocks x 256 threads).
// Stage A: build the two needed intermediate rows (round-1 math, verbatim).
// Stage B: thread t owns 15 contiguous pixels [15t, 15t+15) -- exactly 1/16
// of one cell (cell width 240 px). All taps register-resident (3x float4 per
// row). Per-cell max via 16-lane shuffle; one global atomic per (row,cell).
// Threshold applied at decode: cell valid iff max > 0.65 (identical result).
__global__ __launch_bounds__(256) void scan_kernel(
    const float* __restrict__ sim,
    unsigned long long* __restrict__ cells,
    unsigned long long* __restrict__ bg)
{
    __shared__ float4 I4[2][IW / 4];
    float* I0 = (float*)&I4[0][0];
    float* I1 = (float*)&I4[1][0];

    const float INV375 = (float)(1.0 / 3.75);   // jax inv_scale, f32
    const float INV16  = 0.0625f;

    const int y   = blockIdx.x;
    const int tid = threadIdx.x;

    // second-stage row weights (uniform over block)
    float fy  = ((float)y + 0.5f) * INV375 - 0.5f;
    float fyf = floorf(fy);
    float wy  = fy - fyf;
    int ai = (int)fyf;
    int a1 = min(max(ai + 1, 0), IH - 1);
    int a0 = min(max(ai,     0), IH - 1);

    // Stage A: fill intermediate rows a0, a1 -- ROUND-1 EXPRESSIONS VERBATIM
    for (int r = 0; r < 2; ++r) {
        int a = (r == 0) ? a0 : a1;
        float fa  = ((float)a + 0.5f) * INV16 - 0.5f;
        float faf = floorf(fa);
        float wa  = fa - faf;
        int si = (int)faf;
        int s1 = min(max(si + 1, 0), 63);
        int s0 = min(max(si,     0), 63);
        const float* row0 = sim + s0 * 64;
        const float* row1 = sim + s1 * 64;
        float* dst = (r == 0) ? I0 : I1;
        for (int b = tid; b < IW; b += 256) {
            float fb  = ((float)b + 0.5f) * INV16 - 0.5f;
            float fbf = floorf(fb);
            float wb  = fb - fbf;
            int ci = (int)fbf;
            int c1 = min(max(ci + 1, 0), 63);
            int c0 = min(max(ci,     0), 63);
            float v0 = row0[c0] * (1.f - wb) + row0[c1] * wb;
            float v1 = row1[c0] * (1.f - wb) + row1[c1] * wb;
            dst[b] = v0 * (1.f - wa) + v1 * wa;
        }
    }
    __syncthreads();

    unsigned long long bestCell = 0ull;                    // max-key
    unsigned long long bestBg   = 0xFFFFFFFFFFFFFFFFull;   // min-key
    const int x0 = tid * 15;
    const unsigned int idxBase = (unsigned int)(y * W_OUT + x0);

#define UPD(F, jj) {                                                        \
        unsigned long long top = ((unsigned long long)enc_f32(F)) << 32;    \
        unsigned int idx = idxBase + (jj);                                  \
        unsigned long long bgk = top | (unsigned long long)idx;             \
        unsigned long long ck  = top | (unsigned long long)(~idx);          \
        if (ck  > bestCell) bestCell = ck;                                  \
        if (bgk < bestBg)   bestBg   = bgk;                                 \
    }

    if (tid == 0 || tid == 255) {
        // boundary threads: round-1 clamped per-pixel LDS path (verbatim)
#pragma unroll
        for (int j = 0; j < 15; ++j) {
            int x = x0 + j;
            float fx  = ((float)x + 0.5f) * INV375 - 0.5f;
            float fxf = floorf(fx);
            float wx  = fx - fxf;
            int bi = (int)fxf;
            int b1 = min(max(bi + 1, 0), IW - 1);
            int b0 = min(max(bi,     0), IW - 1);
            float v0 = I0[b0] * (1.f - wx) + I0[b1] * wx;
            float v1 = I1[b0] * (1.f - wx) + I1[b1] * wx;
            float F  = v0 * (1.f - wy) + v1 * wy;
            UPD(F, j)
        }
    } else {
        // interior: taps live in R[4t-4 .. 4t+7]; pixel j uses static window
        // index i0 = 3 + floor((j+0.5)/3.75 - 0.5) + 1  (margins >= 0.033)
        float4 A0 = I4[0][tid - 1], B0 = I4[0][tid], C0 = I4[0][tid + 1];
        float4 A1 = I4[1][tid - 1], B1 = I4[1][tid], C1 = I4[1][tid + 1];
        const float rr0[12] = {A0.x,A0.y,A0.z,A0.w, B0.x,B0.y,B0.z,B0.w, C0.x,C0.y,C0.z,C0.w};
        const float rr1[12] = {A1.x,A1.y,A1.z,A1.w, B1.x,B1.y,B1.z,B1.w, C1.x,C1.y,C1.z,C1.w};

#define PX(j, i0) {                                                         \
            float fx  = ((float)(x0 + (j)) + 0.5f) * INV375 - 0.5f;         \
            float fxf = floorf(fx);                                         \
            float wx  = fx - fxf;                                           \
            float v0 = rr0[(i0)] * (1.f - wx) + rr0[(i0) + 1] * wx;         \
            float v1 = rr1[(i0)] * (1.f - wx) + rr1[(i0) + 1] * wx;         \
            float F  = v0 * (1.f - wy) + v1 * wy;                           \
            UPD(F, j)                                                       \
        }
        PX(0,3)  PX(1,3)  PX(2,4)  PX(3,4)  PX(4,4)
        PX(5,4)  PX(6,5)  PX(7,5)  PX(8,5)  PX(9,6)
        PX(10,6) PX(11,6) PX(12,6) PX(13,7) PX(14,7)
#undef PX
    }
#undef UPD

    // per-cell max: 16 threads own one cell -> xor-shuffle within 16 lanes
#pragma unroll
    for (int m = 1; m <= 8; m <<= 1) {
        unsigned long long o = __shfl_xor(bestCell, m, 64);
        if (o > bestCell) bestCell = o;
    }
    if ((tid & 15) == 0) {
        int seg = (y / 240) * 16 + (tid >> 4);
        atomicMax(&cells[seg], bestCell);
    }

    // global argmin: full-wave xor-shuffle, one atomic per wave
#pragma unroll
    for (int m = 1; m <= 32; m <<= 1) {
        unsigned long long o = __shfl_xor(bestBg, m, 64);
        if (o < bestBg) bestBg = o;
    }
    if ((tid & 63) == 0) atomicMin(bg, bestBg);
}

// Kernel 3: decode 256 cells, apply threshold, stable rank-sort, write output.
__global__ __launch_bounds__(256) void finalize_kernel(
    const unsigned long long* __restrict__ cells,
    const unsigned long long* __restrict__ bg,
    float* __restrict__ out)
{
    __shared__ float sk[256];
    const int t = threadIdx.x;
    unsigned long long ck = cells[t];
    float px = -1.f, py = -1.f, ps = -1.f;
    float key = -__builtin_huge_valf();
    unsigned int e = (unsigned int)(ck >> 32);
    unsigned int b = (e & 0x80000000u) ? (e ^ 0x80000000u) : ~e;
    float v = __uint_as_float(b);     // ck==0 decodes to NaN -> invalid
    if (v > 0.65f) {
        unsigned int idx = ~((unsigned int)(ck & 0xFFFFFFFFull));
        px = (float)(idx % W_OUT);
        py = (float)(idx / W_OUT);
        ps = v;
        key = v;
    }
    sk[t] = key;
    __syncthreads();
    int rank = 0;
    for (int j = 0; j < 256; ++j) {
        float kj = sk[j];
        if (kj > key || (kj == key && j < t)) rank++;
    }
    out[rank * 3 + 0] = px;
    out[rank * 3 + 1] = py;
    out[rank * 3 + 2] = ps;
    if (t == 0) {
        unsigned long long bk = *bg;
        unsigned int idx = (unsigned int)(bk & 0xFFFFFFFFull);
        out[256 * 3 + 0] = (float)(idx % W_OUT);  // bg col (x)
        out[256 * 3 + 1] = (float)(idx / W_OUT);  // bg row (y)
    }
}

extern "C" void kernel_launch(void* const* d_in, const int* in_sizes, int n_in,
                              void* d_out, int out_size, void* d_ws, size_t ws_size,
                              hipStream_t stream) {
    (void)in_sizes; (void)n_in; (void)out_size; (void)ws_size;
    const float* emb = (const float*)d_in[0];   // (1,256,64,64) f32
    const float* ref = (const float*)d_in[1];   // (1,256) f32
    // d_in[2] = ori_shape (2160,3840) -- baked as constants per reference trace
    float* out = (float*)d_out;                 // 256*3 points + 2 bg coords

    float* sim = (float*)d_ws;                                               // 4096 f32
    unsigned long long* cells = (unsigned long long*)((char*)d_ws + 4096*4); // 256 u64
    unsigned long long* bg    = cells + 256;                                 // 1 u64

    sim_kernel<<<64, 256, 0, stream>>>(emb, ref, sim, cells, bg);
    scan_kernel<<<H_OUT, 256, 0, stream>>>(sim, cells, bg);
    finalize_kernel<<<1, 256, 0, stream>>>(cells, bg, out);
}

// Round 3
// 99.618 us; speedup vs baseline: 1.7468x; 1.7468x over previous
//
#include <hip/hip_runtime.h>

#define W_OUT 3840
#define H_OUT 2160
#define IW 1024   // intermediate (cropped) cols
#define IH 576    // intermediate (cropped) rows

__device__ __forceinline__ unsigned int enc_f32(float f) {
    // order-preserving float->uint map (monotone for ALL floats)
    unsigned int b = __float_as_uint(f);
    return b ^ (0x80000000u | (unsigned int)((int)b >> 31));
}

// Kernel 1: sim64[p] = sum_c ref[c]*emb[c][p] / sqrt(sum_c emb[c][p]^2)
// KEEP ARITHMETIC EXACTLY AS ROUND 1 (bitwise-matched the reference).
__global__ __launch_bounds__(256) void sim_kernel(
    const float* __restrict__ emb, const float* __restrict__ ref,
    float* __restrict__ sim)
{
    const int lane = threadIdx.x & 63;
    const int wave = threadIdx.x >> 6;
    const int p = blockIdx.x * 64 + lane;
    const int cbase = wave * 64;
    float dot = 0.f, ss = 0.f;
#pragma unroll 8
    for (int cc = 0; cc < 64; ++cc) {
        int c = cbase + cc;
        float a = emb[c * 4096 + p];
        dot = fmaf(ref[c], a, dot);
        ss  = fmaf(a, a, ss);
    }
    __shared__ float sdot[4][64];
    __shared__ float sss[4][64];
    sdot[wave][lane] = dot;
    sss[wave][lane]  = ss;
    __syncthreads();
    if (wave == 0) {
        float d = (sdot[0][lane] + sdot[1][lane]) + (sdot[2][lane] + sdot[3][lane]);
        float s = (sss[0][lane] + sss[1][lane]) + (sss[2][lane] + sss[3][lane]);
        sim[p] = d / sqrtf(s);
    }
}

// Kernel 2: one block per output row y (2160 blocks x 256 threads).
// Per-pixel math VERBATIM from round 2 (absmax 0.0). NO GLOBAL ATOMICS:
// block writes 16 cell-keys + 1 bg-key to distinct partial slots.
__global__ __launch_bounds__(256) void scan_kernel(
    const float* __restrict__ sim,
    unsigned long long* __restrict__ cellPart,   // [2160][16] max-keys
    unsigned long long* __restrict__ bgPart)     // [2160]     min-keys
{
    __shared__ float4 I4[2][IW / 4];
    __shared__ unsigned long long wmin[4];
    float* I0 = (float*)&I4[0][0];
    float* I1 = (float*)&I4[1][0];

    const float INV375 = (float)(1.0 / 3.75);   // jax inv_scale, f32
    const float INV16  = 0.0625f;

    const int y   = blockIdx.x;
    const int tid = threadIdx.x;

    // second-stage row weights (uniform over block)
    float fy  = ((float)y + 0.5f) * INV375 - 0.5f;
    float fyf = floorf(fy);
    float wy  = fy - fyf;
    int ai = (int)fyf;
    int a1 = min(max(ai + 1, 0), IH - 1);
    int a0 = min(max(ai,     0), IH - 1);

    // Stage A: fill intermediate rows a0, a1 -- ROUND-1 EXPRESSIONS VERBATIM
    for (int r = 0; r < 2; ++r) {
        int a = (r == 0) ? a0 : a1;
        float fa  = ((float)a + 0.5f) * INV16 - 0.5f;
        float faf = floorf(fa);
        float wa  = fa - faf;
        int si = (int)faf;
        int s1 = min(max(si + 1, 0), 63);
        int s0 = min(max(si,     0), 63);
        const float* row0 = sim + s0 * 64;
        const float* row1 = sim + s1 * 64;
        float* dst = (r == 0) ? I0 : I1;
        for (int b = tid; b < IW; b += 256) {
            float fb  = ((float)b + 0.5f) * INV16 - 0.5f;
            float fbf = floorf(fb);
            float wb  = fb - fbf;
            int ci = (int)fbf;
            int c1 = min(max(ci + 1, 0), 63);
            int c0 = min(max(ci,     0), 63);
            float v0 = row0[c0] * (1.f - wb) + row0[c1] * wb;
            float v1 = row1[c0] * (1.f - wb) + row1[c1] * wb;
            dst[b] = v0 * (1.f - wa) + v1 * wa;
        }
    }
    __syncthreads();

    unsigned long long bestCell = 0ull;                    // max-key
    unsigned long long bestBg   = 0xFFFFFFFFFFFFFFFFull;   // min-key
    const int x0 = tid * 15;
    const unsigned int idxBase = (unsigned int)(y * W_OUT + x0);

#define UPD(F, jj) {                                                        \
        unsigned long long top = ((unsigned long long)enc_f32(F)) << 32;    \
        unsigned int idx = idxBase + (jj);                                  \
        unsigned long long bgk = top | (unsigned long long)idx;             \
        unsigned long long ck  = top | (unsigned long long)(~idx);          \
        if (ck  > bestCell) bestCell = ck;                                  \
        if (bgk < bestBg)   bestBg   = bgk;                                 \
    }

    if (tid == 0 || tid == 255) {
        // boundary threads: round-1 clamped per-pixel LDS path (verbatim)
#pragma unroll
        for (int j = 0; j < 15; ++j) {
            int x = x0 + j;
            float fx  = ((float)x + 0.5f) * INV375 - 0.5f;
            float fxf = floorf(fx);
            float wx  = fx - fxf;
            int bi = (int)fxf;
            int b1 = min(max(bi + 1, 0), IW - 1);
            int b0 = min(max(bi,     0), IW - 1);
            float v0 = I0[b0] * (1.f - wx) + I0[b1] * wx;
            float v1 = I1[b0] * (1.f - wx) + I1[b1] * wx;
            float F  = v0 * (1.f - wy) + v1 * wy;
            UPD(F, j)
        }
    } else {
        // interior: taps live in R[4t-4 .. 4t+7]; pixel j uses static window
        // index i0 = 3 + floor((j+0.5)/3.75 - 0.5) + 1  (margins >= 0.033)
        float4 A0 = I4[0][tid - 1], B0 = I4[0][tid], C0 = I4[0][tid + 1];
        float4 A1 = I4[1][tid - 1], B1 = I4[1][tid], C1 = I4[1][tid + 1];
        const float rr0[12] = {A0.x,A0.y,A0.z,A0.w, B0.x,B0.y,B0.z,B0.w, C0.x,C0.y,C0.z,C0.w};
        const float rr1[12] = {A1.x,A1.y,A1.z,A1.w, B1.x,B1.y,B1.z,B1.w, C1.x,C1.y,C1.z,C1.w};

#define PX(j, i0) {                                                         \
            float fx  = ((float)(x0 + (j)) + 0.5f) * INV375 - 0.5f;         \
            float fxf = floorf(fx);                                         \
            float wx  = fx - fxf;                                           \
            float v0 = rr0[(i0)] * (1.f - wx) + rr0[(i0) + 1] * wx;         \
            float v1 = rr1[(i0)] * (1.f - wx) + rr1[(i0) + 1] * wx;         \
            float F  = v0 * (1.f - wy) + v1 * wy;                           \
            UPD(F, j)                                                       \
        }
        PX(0,3)  PX(1,3)  PX(2,4)  PX(3,4)  PX(4,4)
        PX(5,4)  PX(6,5)  PX(7,5)  PX(8,5)  PX(9,6)
        PX(10,6) PX(11,6) PX(12,6) PX(13,7) PX(14,7)
#undef PX
    }
#undef UPD

    // per-cell max: 16 threads own one cell -> xor-shuffle within 16 lanes
#pragma unroll
    for (int m = 1; m <= 8; m <<= 1) {
        unsigned long long o = __shfl_xor(bestCell, m, 64);
        if (o > bestCell) bestCell = o;
    }
    if ((tid & 15) == 0) cellPart[y * 16 + (tid >> 4)] = bestCell;

    // bg argmin: wave xor-shuffle, then 4 wave leaders -> LDS -> one store
#pragma unroll
    for (int m = 1; m <= 32; m <<= 1) {
        unsigned long long o = __shfl_xor(bestBg, m, 64);
        if (o < bestBg) bestBg = o;
    }
    if ((tid & 63) == 0) wmin[tid >> 6] = bestBg;
    __syncthreads();
    if (tid == 0) {
        unsigned long long b0 = wmin[0] < wmin[1] ? wmin[0] : wmin[1];
        unsigned long long b1 = wmin[2] < wmin[3] ? wmin[2] : wmin[3];
        bgPart[y] = b0 < b1 ? b0 : b1;
    }
}

// Kernel 3: reduce partials (no atomics were used), apply threshold,
// stable rank-sort by score desc, write output.
__global__ __launch_bounds__(256) void finalize_kernel(
    const unsigned long long* __restrict__ cellPart,
    const unsigned long long* __restrict__ bgPart,
    float* __restrict__ out)
{
    __shared__ float sk[256];
    __shared__ unsigned long long sb[256];
    const int t = threadIdx.x;

    // --- per-cell max over the 240 rows of its band (bands 0..8 populated) ---
    unsigned long long best = 0ull;
    if (t < 144) {
        const int band = t >> 4, cx = t & 15;
        const unsigned long long* p = cellPart + (band * 240) * 16 + cx;
#pragma unroll 8
        for (int r = 0; r < 240; ++r) {
            unsigned long long k = p[r * 16];
            if (k > best) best = k;
        }
    }
    float px = -1.f, py = -1.f, ps = -1.f;
    float key = -__builtin_huge_valf();
    if (best != 0ull) {
        unsigned int e = (unsigned int)(best >> 32);
        unsigned int b = (e & 0x80000000u) ? (e ^ 0x80000000u) : ~e;
        float v = __uint_as_float(b);
        if (v > 0.65f) {
            unsigned int idx = ~((unsigned int)(best & 0xFFFFFFFFull));
            px = (float)(idx % W_OUT);
            py = (float)(idx / W_OUT);
            ps = v;
            key = v;
        }
    }

    // --- global argmin over 2160 row minima ---
    unsigned long long m = 0xFFFFFFFFFFFFFFFFull;
    for (int i = t; i < H_OUT; i += 256) {
        unsigned long long k = bgPart[i];
        if (k < m) m = k;
    }
    sb[t] = m;
    __syncthreads();
    for (int s = 128; s > 0; s >>= 1) {
        if (t < s) {
            unsigned long long o = sb[t + s];
            if (o < sb[t]) sb[t] = o;
        }
        __syncthreads();
    }

    // --- stable rank-sort (desc by score, ties by cell index) ---
    sk[t] = key;
    __syncthreads();
    int rank = 0;
    for (int j = 0; j < 256; ++j) {
        float kj = sk[j];
        if (kj > key || (kj == key && j < t)) rank++;
    }
    out[rank * 3 + 0] = px;
    out[rank * 3 + 1] = py;
    out[rank * 3 + 2] = ps;
    if (t == 0) {
        unsigned int idx = (unsigned int)(sb[0] & 0xFFFFFFFFull);
        out[256 * 3 + 0] = (float)(idx % W_OUT);  // bg col (x)
        out[256 * 3 + 1] = (float)(idx / W_OUT);  // bg row (y)
    }
}

extern "C" void kernel_launch(void* const* d_in, const int* in_sizes, int n_in,
                              void* d_out, int out_size, void* d_ws, size_t ws_size,
                              hipStream_t stream) {
    (void)in_sizes; (void)n_in; (void)out_size; (void)ws_size;
    const float* emb = (const float*)d_in[0];   // (1,256,64,64) f32
    const float* ref = (const float*)d_in[1];   // (1,256) f32
    // d_in[2] = ori_shape (2160,3840) -- baked as constants per reference trace
    float* out = (float*)d_out;                 // 256*3 points + 2 bg coords

    float* sim = (float*)d_ws;                                                 // 4096 f32 (16 KB)
    unsigned long long* cellPart = (unsigned long long*)((char*)d_ws + 16384); // 2160*16 u64
    unsigned long long* bgPart   = cellPart + H_OUT * 16;                      // 2160 u64

    sim_kernel<<<64, 256, 0, stream>>>(emb, ref, sim);
    scan_kernel<<<H_OUT, 256, 0, stream>>>(sim, cellPart, bgPart);
    finalize_kernel<<<1, 256, 0, stream>>>(cellPart, bgPart, out);
}